// Round 10
// baseline (336.844 us; speedup 1.0000x reference)
//
#include <hip/hip_runtime.h>
#include <math.h>

#define BB 2
#define TT 4096
#define CC 64
#define HH 4
#define DH 16
#define NROW (BB*TT)                 // 8192
#define NBLK (NROW/16)               // 512
#define SCALE 0.36067376022224085f   // 0.25 * log2(e)

typedef __fp16 h4 __attribute__((ext_vector_type(4)));
typedef __fp16 h2 __attribute__((ext_vector_type(2)));
typedef __fp16 h8 __attribute__((ext_vector_type(8)));
typedef float  f4 __attribute__((ext_vector_type(4)));
typedef float  f16v __attribute__((ext_vector_type(16)));

union U4H8 { uint4 u; h8 h; };
union UWH8 { unsigned u[4]; h8 h; };

// ---- sense-reversing grid barrier on module-scope globals ----
// Not in d_ws -> immune to the harness's workspace re-poison; self-resetting
// (count returns to 0, gen monotonically increases) -> no per-launch memset and
// safe under graph replay.  Requires all blocks co-resident: 512 blocks x 4
// waves, LDS 18.4KB/block, launch_bounds(256,2) caps VGPR<=256 -> 2 blocks/CU
// across 256 CUs = exactly 512 resident.  __syncthreads drains the block's
// stores (vmcnt(0) before s_barrier); __threadfence (agent scope) write-backs
// the producer L2 (release) / invalidates consumer L1+L2 (acquire) -- the same
// pair that implicit kernel boundaries provide in the 3-kernel version.
__device__ unsigned bar_count = 0;
__device__ unsigned bar_gen   = 0;

__device__ __forceinline__ void grid_barrier() {
    __syncthreads();
    __threadfence();                              // release
    if (threadIdx.x == 0) {
        unsigned gen = __hip_atomic_load(&bar_gen, __ATOMIC_ACQUIRE,
                                         __HIP_MEMORY_SCOPE_AGENT);
        unsigned arrived = __hip_atomic_fetch_add(&bar_count, 1u, __ATOMIC_ACQ_REL,
                                                  __HIP_MEMORY_SCOPE_AGENT) + 1u;
        if (arrived == (unsigned)NBLK) {
            __hip_atomic_store(&bar_count, 0u, __ATOMIC_RELAXED,
                               __HIP_MEMORY_SCOPE_AGENT);
            __hip_atomic_store(&bar_gen, gen + 1u, __ATOMIC_RELEASE,
                               __HIP_MEMORY_SCOPE_AGENT);
        } else {
            while (__hip_atomic_load(&bar_gen, __ATOMIC_ACQUIRE,
                                     __HIP_MEMORY_SCOPE_AGENT) == gen)
                __builtin_amdgcn_s_sleep(2);
        }
    }
    __threadfence();                              // acquire
    __syncthreads();
}

// ---------------- Fused kernel: qkv -> barrier -> attn -> barrier -> proj ----------------
// 512 blocks x 256 thr.  Phase bodies byte-identical to the best measured
// versions (qkv/attn = round 6, proj = round 0); only the sync mechanism is new.
//   qkv : block = 16 rows; Q,K [bh][T][16] f16; VT k16-grouped KEY-PERMUTED
//         [bh][chunk:64][sub:4][d:32][slot:16], slots [0-3,8-11,4-7,12-15];
//         d rows 16..31 pad, rows 16/20 = 1.0 (PV MFMA accumulates L free).
//   attn: block = (head = blockIdx&7 [XCD affinity], 64-row qtile); wave=ksplit;
//         QK 32x32x16, swap-free P assembly, pad-ones denominator.
//   proj: block = 16 rows; wave -> 16-col o-slice.
__global__ __launch_bounds__(256, 2) void fused_kernel(
        const float* __restrict__ x,
        const float* __restrict__ w_attn, const float* __restrict__ b_attn,
        const float* __restrict__ w_proj, const float* __restrict__ b_proj,
        float* __restrict__ out,
        __fp16* __restrict__ Q, __fp16* __restrict__ K,
        __fp16* __restrict__ VT, __fp16* __restrict__ yh)
{
    __shared__ union {
        __fp16 smv[64][16];          // qkv phase: V-transpose staging
        float  Osm[4][2][64][9];     // attn phase: [ksplit][qtile][lane][reg0..7, L]
    } sh;

    const int t = threadIdx.x;
    const int wave = t >> 6, lane = t & 63;
    const int lq = lane & 15, g = lane >> 4;

    // ================= Phase 1: qkv GEMM =================
    {
        const int r0 = blockIdx.x*16;
        const int b = r0 >> 12, tt0 = r0 & (TT-1);

        h4 xb[4];
        const float* xrow = x + (size_t)(r0 + lq)*CC;
        #pragma unroll
        for (int s = 0; s < 4; s++) {
            float4 xv = *(const float4*)(xrow + s*16 + g*4);
            h2 lo = __builtin_amdgcn_cvt_pkrtz(xv.x, xv.y);
            h2 hi = __builtin_amdgcn_cvt_pkrtz(xv.z, xv.w);
            xb[s] = (h4){lo.x, lo.y, hi.x, hi.y};
        }

        #pragma unroll
        for (int j = 0; j < 3; j++) {
            const int nt = wave*3 + j;
            const int o0 = nt*16;
            const float sc = (nt < 4) ? SCALE : 1.0f;
            float4 bv = *(const float4*)(b_attn + o0 + g*4);
            f4 acc = {bv.x*sc, bv.y*sc, bv.z*sc, bv.w*sc};
            #pragma unroll
            for (int s = 0; s < 4; s++) {
                float4 wv = *(const float4*)(w_attn + (size_t)(o0 + lq)*CC + s*16 + g*4);
                h2 lo = __builtin_amdgcn_cvt_pkrtz(wv.x*sc, wv.y*sc);
                h2 hi = __builtin_amdgcn_cvt_pkrtz(wv.z*sc, wv.w*sc);
                h4 af = (h4){lo.x, lo.y, hi.x, hi.y};
                acc = __builtin_amdgcn_mfma_f32_16x16x16f16(af, xb[s], acc, 0, 0, 0);
            }
            h2 plo = __builtin_amdgcn_cvt_pkrtz(acc.x, acc.y);
            h2 phi = __builtin_amdgcn_cvt_pkrtz(acc.z, acc.w);
            h4 pk = (h4){plo.x, plo.y, phi.x, phi.y};
            if (nt < 8) {
                const int part = nt >> 2, h = nt & 3;
                __fp16* dst = (part == 0) ? Q : K;
                *(h4*)(dst + ((size_t)(b*HH + h)*TT + tt0 + lq)*DH + g*4) = pk;
            } else {
                const int h = nt - 8;
                sh.smv[h*16 + g*4 + 0][lq] = pk.x;
                sh.smv[h*16 + g*4 + 1][lq] = pk.y;
                sh.smv[h*16 + g*4 + 2][lq] = pk.z;
                sh.smv[h*16 + g*4 + 3][lq] = pk.w;
            }
        }
        __syncthreads();
        if (t < 64) {
            const int h = t >> 4, d = t & 15;
            uint4 v0 = *(const uint4*)&sh.smv[t][0];   // keys 0..7
            uint4 v1 = *(const uint4*)&sh.smv[t][8];   // keys 8..15
            uint4 pa = {v0.x, v0.y, v1.x, v1.y};       // slots 0..7
            uint4 pb = {v0.z, v0.w, v1.z, v1.w};       // slots 8..15
            __fp16* dst = VT + (size_t)(b*HH + h)*TT*32
                            + (size_t)(tt0 >> 6)*2048
                            + (size_t)((tt0 & 63) >> 4)*512
                            + (size_t)d*16;
            *(uint4*)dst = pa;
            *(uint4*)(dst + 8) = pb;
            const unsigned cb = (d == 0 || d == 4) ? 0x3C003C00u : 0u;
            const uint4 cv = {cb, cb, cb, cb};
            __fp16* dst2 = dst + 16*16;
            *(uint4*)dst2 = cv;
            *(uint4*)(dst2 + 8) = cv;
        }
    }

    grid_barrier();

    // ================= Phase 2: flash attention =================
    {
        const int l31 = lane & 31, hi = lane >> 5;
        const int head = blockIdx.x & 7;     // XCD-head affinity
        const int qt   = blockIdx.x >> 3;
        const int q0 = qt*64;
        const __fp16* Qh = Q  + (size_t)head*TT*DH;
        const __fp16* Kh = K  + (size_t)head*TT*DH;
        const __fp16* Vh = VT + (size_t)head*TT*32;

        U4H8 qf0, qf1;
        qf0.u = *(const uint4*)(Qh + (size_t)(q0 + l31)*DH + hi*8);
        qf1.u = *(const uint4*)(Qh + (size_t)(q0 + 32 + l31)*DH + hi*8);

        const f16v Zf = {0.f,0.f,0.f,0.f,0.f,0.f,0.f,0.f,0.f,0.f,0.f,0.f,0.f,0.f,0.f,0.f};
        f16v O0 = Zf, O1 = Zf;

        const __fp16* kbase = Kh + (size_t)(wave*1024 + l31)*DH + hi*8;
        const __fp16* vbase = Vh + (size_t)(wave*16)*2048 + l31*16 + hi*8;

        const int start = (blockIdx.x*5 + wave*3) & 15;

        uint4 ka[2], va[4], kb[2], vb[4];

#define LOADC(c, KF, VF)                                                   \
    {  const size_t cc_ = (size_t)(c);                                     \
       _Pragma("unroll") for (int kt_ = 0; kt_ < 2; kt_++)                 \
           KF[kt_] = *(const uint4*)(kbase + cc_*1024 + kt_*512);          \
       _Pragma("unroll") for (int s_ = 0; s_ < 4; s_++)                    \
           VF[s_] = *(const uint4*)(vbase + cc_*2048 + s_*512);            \
    }

        LOADC(start, ka, va)

#define PROC_TILE(S, O, VF)                                                        \
    {   float p_[16]; unsigned W_[8];                                              \
        _Pragma("unroll") for (int r_ = 0; r_ < 16; r_++)                          \
            p_[r_] = __builtin_amdgcn_exp2f(S[r_]);                                \
        _Pragma("unroll") for (int m_ = 0; m_ < 8; m_++)                           \
            W_[m_] = __builtin_bit_cast(unsigned,                                  \
                __builtin_amdgcn_cvt_pkrtz(p_[2*m_], p_[2*m_+1]));                 \
        _Pragma("unroll") for (int s2 = 0; s2 < 2; s2++) {                         \
            UWH8 bw_;                                                              \
            bw_.u[0] = W_[4*s2+0];  bw_.u[1] = W_[4*s2+1];                         \
            bw_.u[2] = W_[4*s2+2];  bw_.u[3] = W_[4*s2+3];                         \
            U4H8 vv_; vv_.u = VF[kt*2+s2];                                         \
            O = __builtin_amdgcn_mfma_f32_32x32x16_f16(vv_.h, bw_.h, O, 0,0,0);    \
        }                                                                          \
    }

#define ATTN_CHUNK(KF, VF)                                                         \
    _Pragma("unroll")                                                              \
    for (int kt = 0; kt < 2; kt++) {                                               \
        U4H8 ak_; ak_.u = KF[kt];                                                  \
        f16v S0 = __builtin_amdgcn_mfma_f32_32x32x16_f16(ak_.h, qf0.h, Zf, 0,0,0); \
        f16v S1 = __builtin_amdgcn_mfma_f32_32x32x16_f16(ak_.h, qf1.h, Zf, 0,0,0); \
        PROC_TILE(S0, O0, VF)                                                      \
        PROC_TILE(S1, O1, VF)                                                      \
    }

        for (int it = 0; it < 16; it += 2) {
            LOADC((start + it + 1) & 15, kb, vb)
            ATTN_CHUNK(ka, va)
            LOADC((start + it + 2) & 15, ka, va)   // wraps on last iter (redundant, harmless)
            ATTN_CHUNK(kb, vb)
        }
#undef ATTN_CHUNK
#undef PROC_TILE
#undef LOADC

        __syncthreads();   // phase-1 smv long done; re-purpose LDS as Osm
        #pragma unroll
        for (int r = 0; r < 9; r++) {
            sh.Osm[wave][0][lane][r] = O0[r];
            sh.Osm[wave][1][lane][r] = O1[r];
        }
        __syncthreads();
        if (wave < 2) {
            const int qt2 = wave;
            float a[9];
            #pragma unroll
            for (int r = 0; r < 9; r++)
                a[r] = sh.Osm[0][qt2][lane][r] + sh.Osm[1][qt2][lane][r]
                     + sh.Osm[2][qt2][lane][r] + sh.Osm[3][qt2][lane][r];
            const float rinv = 1.f / a[8];
            h2 plo = __builtin_amdgcn_cvt_pkrtz(a[0]*rinv, a[1]*rinv);
            h2 phi = __builtin_amdgcn_cvt_pkrtz(a[2]*rinv, a[3]*rinv);
            h4 pk1 = (h4){plo.x, plo.y, phi.x, phi.y};
            plo = __builtin_amdgcn_cvt_pkrtz(a[4]*rinv, a[5]*rinv);
            phi = __builtin_amdgcn_cvt_pkrtz(a[6]*rinv, a[7]*rinv);
            h4 pk2 = (h4){plo.x, plo.y, phi.x, phi.y};
            const int b = head >> 2, hh = head & 3;
            const size_t q = (size_t)q0 + qt2*32 + l31;
            __fp16* dst = yh + ((size_t)b*TT + q)*CC + hh*DH + hi*4;
            *(h4*)dst = pk1;
            *(h4*)(dst + 8) = pk2;
        }
    }

    grid_barrier();

    // ================= Phase 3: proj =================
    {
        const int r0 = blockIdx.x*16;
        const int o0 = wave*16;

        h4 yb[4];
        const __fp16* yrow = yh + (size_t)(r0 + lq)*CC;
        #pragma unroll
        for (int s = 0; s < 4; s++) yb[s] = *(const h4*)(yrow + s*16 + g*4);

        float4 bv = *(const float4*)(b_proj + o0 + g*4);
        f4 acc = {bv.x, bv.y, bv.z, bv.w};
        #pragma unroll
        for (int s = 0; s < 4; s++) {
            float4 wv = *(const float4*)(w_proj + (size_t)(o0 + lq)*CC + s*16 + g*4);
            h2 lo = __builtin_amdgcn_cvt_pkrtz(wv.x, wv.y);
            h2 hi = __builtin_amdgcn_cvt_pkrtz(wv.z, wv.w);
            h4 af = (h4){lo.x, lo.y, hi.x, hi.y};
            acc = __builtin_amdgcn_mfma_f32_16x16x16f16(af, yb[s], acc, 0, 0, 0);
        }
        *(float4*)(out + (size_t)(r0 + lq)*CC + o0 + g*4) = (float4){acc.x, acc.y, acc.z, acc.w};
    }
}

extern "C" void kernel_launch(void* const* d_in, const int* in_sizes, int n_in,
                              void* d_out, int out_size, void* d_ws, size_t ws_size,
                              hipStream_t stream) {
    const float* x      = (const float*)d_in[0];
    const float* w_attn = (const float*)d_in[1];
    const float* b_attn = (const float*)d_in[2];
    const float* w_proj = (const float*)d_in[3];
    const float* b_proj = (const float*)d_in[4];
    float* out = (float*)d_out;

    const size_t headszQK = (size_t)BB*HH*TT*DH;   // Q,K: 512K halves each
    const size_t vtsz     = (size_t)BB*HH*TT*32;   // VT (d-expanded): 1M halves
    __fp16* Q   = (__fp16*)d_ws;
    __fp16* K   = Q + headszQK;
    __fp16* VT  = K + headszQK;
    __fp16* yh  = VT + vtsz;

    fused_kernel<<<NBLK, 256, 0, stream>>>(x, w_attn, b_attn, w_proj, b_proj,
                                           out, Q, K, VT, yh);
}

// Round 11
// 131.678 us; speedup vs baseline: 2.5581x; 2.5581x over previous
//
#include <hip/hip_runtime.h>
#include <math.h>

#define BB 2
#define TT 4096
#define CC 64
#define HH 4
#define DH 16
#define NROW (BB*TT)                 // 8192
#define SCALE 0.36067376022224085f   // 0.25 * log2(e)

typedef __fp16 h4 __attribute__((ext_vector_type(4)));
typedef __fp16 h2 __attribute__((ext_vector_type(2)));
typedef __fp16 h8 __attribute__((ext_vector_type(8)));
typedef float  f4 __attribute__((ext_vector_type(4)));
typedef float  f16v __attribute__((ext_vector_type(16)));

union U4H8 { uint4 u; h8 h; };
union UWH8 { unsigned u[4]; h8 h; };

// ---------------- Kernel A: qkv GEMM (round-6 proven version, unchanged) ----------------
// 512 blocks x 256 thr: block = 16 rows; wave w -> output tiles w*3..w*3+2 (of 12)
// Q,K: [bh][T][16] f16.
// VT k16-grouped, K-PERMUTED layout: [bh][chunk:64][sub:4][d:32][slot:16] f16
//   slot order holds keys sigma = [0,1,2,3,8,9,10,11,4,5,6,7,12,13,14,15]
//   (involution) so the attn PV B-operand is exactly the lane's own packed
//   exp2(S) registers.  d rows 0..15 = V^T; rows 16..31 = pad, rows 16/20 = 1.0
//   (PV MFMA accumulates L = sum(exp) into acc reg 8 free), rest 0.
__global__ __launch_bounds__(256) void qkv_kernel(const float* __restrict__ x,
        const float* __restrict__ w, const float* __restrict__ bias,
        __fp16* __restrict__ Q, __fp16* __restrict__ K, __fp16* __restrict__ VT) {
    __shared__ __fp16 smv[64][16];   // [h*16+d][t-col] staging for V transpose
    const int t = threadIdx.x;
    const int wave = t >> 6, lane = t & 63;
    const int lq = lane & 15, g = lane >> 4;
    const int r0 = blockIdx.x*16;
    const int b = r0 >> 12, tt0 = r0 & (TT-1);

    // B-frag (x^T): lane holds x[r0+lq][s*16 + g*4 + j]
    h4 xb[4];
    const float* xrow = x + (size_t)(r0 + lq)*CC;
    #pragma unroll
    for (int s = 0; s < 4; s++) {
        float4 xv = *(const float4*)(xrow + s*16 + g*4);
        h2 lo = __builtin_amdgcn_cvt_pkrtz(xv.x, xv.y);
        h2 hi = __builtin_amdgcn_cvt_pkrtz(xv.z, xv.w);
        xb[s] = (h4){lo.x, lo.y, hi.x, hi.y};
    }

    #pragma unroll
    for (int j = 0; j < 3; j++) {
        const int nt = wave*3 + j;       // tile: o-range [nt*16, nt*16+16)
        const int o0 = nt*16;
        const float sc = (nt < 4) ? SCALE : 1.0f;
        float4 bv = *(const float4*)(bias + o0 + g*4);
        f4 acc = {bv.x*sc, bv.y*sc, bv.z*sc, bv.w*sc};
        #pragma unroll
        for (int s = 0; s < 4; s++) {
            float4 wv = *(const float4*)(w + (size_t)(o0 + lq)*CC + s*16 + g*4);
            h2 lo = __builtin_amdgcn_cvt_pkrtz(wv.x*sc, wv.y*sc);
            h2 hi = __builtin_amdgcn_cvt_pkrtz(wv.z*sc, wv.w*sc);
            h4 af = (h4){lo.x, lo.y, hi.x, hi.y};
            acc = __builtin_amdgcn_mfma_f32_16x16x16f16(af, xb[s], acc, 0, 0, 0);
        }
        h2 plo = __builtin_amdgcn_cvt_pkrtz(acc.x, acc.y);
        h2 phi = __builtin_amdgcn_cvt_pkrtz(acc.z, acc.w);
        h4 pk = (h4){plo.x, plo.y, phi.x, phi.y};
        if (nt < 8) {
            const int part = nt >> 2, h = nt & 3;
            __fp16* dst = (part == 0) ? Q : K;
            *(h4*)(dst + ((size_t)(b*HH + h)*TT + tt0 + lq)*DH + g*4) = pk;
        } else {
            const int h = nt - 8;
            smv[h*16 + g*4 + 0][lq] = pk.x;
            smv[h*16 + g*4 + 1][lq] = pk.y;
            smv[h*16 + g*4 + 2][lq] = pk.z;
            smv[h*16 + g*4 + 3][lq] = pk.w;
        }
    }
    __syncthreads();
    if (t < 64) {                        // row (h,d): 16 t-cols = one k16 group
        const int h = t >> 4, d = t & 15;
        uint4 v0 = *(const uint4*)&smv[t][0];   // keys 0..7
        uint4 v1 = *(const uint4*)&smv[t][8];   // keys 8..15
        // permuted slot order [0,1,2,3,8,9,10,11 | 4,5,6,7,12,13,14,15]
        uint4 pa = {v0.x, v0.y, v1.x, v1.y};    // slots 0..7
        uint4 pb = {v0.z, v0.w, v1.z, v1.w};    // slots 8..15
        __fp16* dst = VT + (size_t)(b*HH + h)*TT*32
                        + (size_t)(tt0 >> 6)*2048           // chunk
                        + (size_t)((tt0 & 63) >> 4)*512     // sub
                        + (size_t)d*16;                     // d row
        *(uint4*)dst = pa;
        *(uint4*)(dst + 8) = pb;
        const unsigned cb = (d == 0 || d == 4) ? 0x3C003C00u : 0u;
        const uint4 cv = {cb, cb, cb, cb};
        __fp16* dst2 = dst + 16*16;
        *(uint4*)dst2 = cv;
        *(uint4*)(dst2 + 8) = cv;
    }
}

// ---------------- Kernel B: flash attention + FUSED proj partial (atomicAdd) ----------------
// 512 blocks x 256 thr.  Main loop byte-identical to round 6 (session best):
// XCD-head affinity (head = blockIdx&7), swap-free P assembly, pad-ones
// denominator, depth-1 ring prefetch.
// NEW epilogue: instead of writing yh for a separate proj kernel, each block
// computes its PARTIAL proj product  out[q][o] += y_slice[q][c_hh] . w_proj[o][c_hh]
// (one head's 16-c slice) with 2x mfma_32x32x16 and atomicAdds into out.
// Layout alignment: the packed normalized y word j on lane(hi) holds
// c = sigma(8*hi+j), sigma = [0-3,8-11,4-7,12-15] -- so loading w_proj's
// A-fragment with sigma-permuted columns (two float4s at +0/+8, offset hi*4)
// makes slot-to-slot contraction exact, zero cross-lane ops.
// Bias is added via the MFMA C operand by hh==0 blocks only; harness zeroes
// `out` before launch, so atomic accumulation over the 4 heads is correct.
__global__ __launch_bounds__(256) void attn_kernel(const __fp16* __restrict__ Q,
        const __fp16* __restrict__ K, const __fp16* __restrict__ VT,
        const float* __restrict__ w_proj, const float* __restrict__ b_proj,
        float* __restrict__ out) {
    __shared__ float Osm[4][2][64][9];   // [ksplit][qtile][lane][reg0..7, L]
    const int t = threadIdx.x;
    const int wave = t >> 6, lane = t & 63;
    const int l31 = lane & 31, hi = lane >> 5;
    const int head = blockIdx.x & 7;     // XCD-head affinity
    const int qt   = blockIdx.x >> 3;
    const int q0 = qt*64;
    const __fp16* Qh = Q  + (size_t)head*TT*DH;
    const __fp16* Kh = K  + (size_t)head*TT*DH;
    const __fp16* Vh = VT + (size_t)head*TT*32;

    // Q fragments (B-operand): col q = l31, d = hi*8 + j  -> 16B loads
    U4H8 qf0, qf1;
    qf0.u = *(const uint4*)(Qh + (size_t)(q0 + l31)*DH + hi*8);
    qf1.u = *(const uint4*)(Qh + (size_t)(q0 + 32 + l31)*DH + hi*8);

    const f16v Zf = {0.f,0.f,0.f,0.f,0.f,0.f,0.f,0.f,0.f,0.f,0.f,0.f,0.f,0.f,0.f,0.f};
    f16v O0 = Zf, O1 = Zf;

    const __fp16* kbase = Kh + (size_t)(wave*1024 + l31)*DH + hi*8;      // + c*1024 + kt*512
    const __fp16* vbase = Vh + (size_t)(wave*16)*2048 + l31*16 + hi*8;   // + c*2048 + s*512

    const int start = (blockIdx.x*5 + wave*3) & 15;   // per-(block,wave) phase

    uint4 ka[2], va[4], kb[2], vb[4];

#define LOADC(c, KF, VF)                                                   \
    {  const size_t cc_ = (size_t)(c);                                     \
       _Pragma("unroll") for (int kt_ = 0; kt_ < 2; kt_++)                 \
           KF[kt_] = *(const uint4*)(kbase + cc_*1024 + kt_*512);          \
       _Pragma("unroll") for (int s_ = 0; s_ < 4; s_++)                    \
           VF[s_] = *(const uint4*)(vbase + cc_*2048 + s_*512);            \
    }

    LOADC(start, ka, va)

#define PROC_TILE(S, O, VF)                                                        \
    {   float p_[16]; unsigned W_[8];                                              \
        _Pragma("unroll") for (int r_ = 0; r_ < 16; r_++)                          \
            p_[r_] = __builtin_amdgcn_exp2f(S[r_]);                                \
        _Pragma("unroll") for (int m_ = 0; m_ < 8; m_++)                           \
            W_[m_] = __builtin_bit_cast(unsigned,                                  \
                __builtin_amdgcn_cvt_pkrtz(p_[2*m_], p_[2*m_+1]));                 \
        _Pragma("unroll") for (int s2 = 0; s2 < 2; s2++) {                         \
            UWH8 bw_;                                                              \
            bw_.u[0] = W_[4*s2+0];  bw_.u[1] = W_[4*s2+1];                         \
            bw_.u[2] = W_[4*s2+2];  bw_.u[3] = W_[4*s2+3];                         \
            U4H8 vv_; vv_.u = VF[kt*2+s2];                                         \
            O = __builtin_amdgcn_mfma_f32_32x32x16_f16(vv_.h, bw_.h, O, 0,0,0);    \
        }                                                                          \
    }

#define ATTN_CHUNK(KF, VF)                                                         \
    _Pragma("unroll")                                                              \
    for (int kt = 0; kt < 2; kt++) {                                               \
        U4H8 ak_; ak_.u = KF[kt];                                                  \
        f16v S0 = __builtin_amdgcn_mfma_f32_32x32x16_f16(ak_.h, qf0.h, Zf, 0,0,0); \
        f16v S1 = __builtin_amdgcn_mfma_f32_32x32x16_f16(ak_.h, qf1.h, Zf, 0,0,0); \
        PROC_TILE(S0, O0, VF)                                                      \
        PROC_TILE(S1, O1, VF)                                                      \
    }

    for (int it = 0; it < 16; it += 2) {
        LOADC((start + it + 1) & 15, kb, vb)
        ATTN_CHUNK(ka, va)
        LOADC((start + it + 2) & 15, ka, va)   // wraps on last iter (redundant, harmless)
        ATTN_CHUNK(kb, vb)
    }
#undef ATTN_CHUNK
#undef PROC_TILE
#undef LOADC

    // split-K combine: O regs 0..7 are d = {0..3,8..11}+4*hi, reg 8 = L
    #pragma unroll
    for (int r = 0; r < 9; r++) {
        Osm[wave][0][lane][r] = O0[r];
        Osm[wave][1][lane][r] = O1[r];
    }
    __syncthreads();
    if (wave < 2) {
        const int qt2 = wave;
        float a[9];
        #pragma unroll
        for (int r = 0; r < 9; r++)
            a[r] = Osm[0][qt2][lane][r] + Osm[1][qt2][lane][r]
                 + Osm[2][qt2][lane][r] + Osm[3][qt2][lane][r];
        const float rinv = 1.f / a[8];

        // packed y B-frag: word j holds c = sigma(8*hi+j) of this head's slice
        h2 w01 = __builtin_amdgcn_cvt_pkrtz(a[0]*rinv, a[1]*rinv);
        h2 w23 = __builtin_amdgcn_cvt_pkrtz(a[2]*rinv, a[3]*rinv);
        h2 w89 = __builtin_amdgcn_cvt_pkrtz(a[4]*rinv, a[5]*rinv);
        h2 wAB = __builtin_amdgcn_cvt_pkrtz(a[6]*rinv, a[7]*rinv);
        UWH8 yb;
        yb.u[0] = __builtin_bit_cast(unsigned, w01);
        yb.u[1] = __builtin_bit_cast(unsigned, w23);
        yb.u[2] = __builtin_bit_cast(unsigned, w89);
        yb.u[3] = __builtin_bit_cast(unsigned, wAB);

        const int bb = head >> 2, hh = head & 3;
        float* orow = out + ((size_t)bb*TT + q0 + qt2*32 + l31)*CC;

        #pragma unroll
        for (int ot = 0; ot < 2; ot++) {
            const int ob = ot*32;
            // A-frag: w_proj[o = ob+l31][c = hh*16 + sigma(8*hi+j)]
            // sigma groups: {0..3, 8..11} (+4*hi) -> two float4 at +0 and +8
            const float* wrow = w_proj + (size_t)(ob + l31)*CC + hh*16 + hi*4;
            float4 g1 = *(const float4*)(wrow);
            float4 g2 = *(const float4*)(wrow + 8);
            h2 p01 = __builtin_amdgcn_cvt_pkrtz(g1.x, g1.y);
            h2 p23 = __builtin_amdgcn_cvt_pkrtz(g1.z, g1.w);
            h2 p89 = __builtin_amdgcn_cvt_pkrtz(g2.x, g2.y);
            h2 pAB = __builtin_amdgcn_cvt_pkrtz(g2.z, g2.w);
            UWH8 af;
            af.u[0] = __builtin_bit_cast(unsigned, p01);
            af.u[1] = __builtin_bit_cast(unsigned, p23);
            af.u[2] = __builtin_bit_cast(unsigned, p89);
            af.u[3] = __builtin_bit_cast(unsigned, pAB);

            // C operand: bias (hh==0 blocks only; others accumulate on zero)
            f16v Cv = Zf;
            if (hh == 0) {
                #pragma unroll
                for (int r = 0; r < 16; r++)
                    Cv[r] = b_proj[ob + (r & 3) + 8*(r >> 2) + 4*hi];
            }
            // D[o][q]: col = l31 = q, row o = (r&3)+8*(r>>2)+4*hi
            f16v D = __builtin_amdgcn_mfma_f32_32x32x16_f16(af.h, yb.h, Cv, 0, 0, 0);
            #pragma unroll
            for (int r = 0; r < 16; r++)
                atomicAdd(orow + ob + (r & 3) + 8*(r >> 2) + 4*hi, D[r]);
        }
    }
}

extern "C" void kernel_launch(void* const* d_in, const int* in_sizes, int n_in,
                              void* d_out, int out_size, void* d_ws, size_t ws_size,
                              hipStream_t stream) {
    const float* x      = (const float*)d_in[0];
    const float* w_attn = (const float*)d_in[1];
    const float* b_attn = (const float*)d_in[2];
    const float* w_proj = (const float*)d_in[3];
    const float* b_proj = (const float*)d_in[4];
    float* out = (float*)d_out;

    const size_t headszQK = (size_t)BB*HH*TT*DH;   // Q,K: 512K halves each
    __fp16* Q   = (__fp16*)d_ws;
    __fp16* K   = Q + headszQK;
    __fp16* VT  = K + headszQK;

    qkv_kernel<<<NROW/16, 256, 0, stream>>>(x, w_attn, b_attn, Q, K, VT);
    attn_kernel<<<BB*HH*(TT/64), 256, 0, stream>>>(Q, K, VT, w_proj, b_proj, out);
}

// Round 12
// 91.071 us; speedup vs baseline: 3.6987x; 1.4459x over previous
//
#include <hip/hip_runtime.h>
#include <math.h>

#define BB 2
#define TT 4096
#define CC 64
#define HH 4
#define DH 16
#define NROW (BB*TT)                 // 8192
#define SCALE 0.36067376022224085f   // 0.25 * log2(e)

typedef __fp16 h4 __attribute__((ext_vector_type(4)));
typedef __fp16 h2 __attribute__((ext_vector_type(2)));
typedef __fp16 h8 __attribute__((ext_vector_type(8)));
typedef float  f4 __attribute__((ext_vector_type(4)));
typedef float  f16v __attribute__((ext_vector_type(16)));

union U4H8 { uint4 u; h8 h; };
union UWH8 { unsigned u[4]; h8 h; };

// ---------------- Kernel A: qkv GEMM (round-6 proven version, unchanged) ----------------
// 512 blocks x 256 thr: block = 16 rows; wave w -> output tiles w*3..w*3+2 (of 12)
// Q,K: [bh][T][16] f16.
// VT k16-grouped, K-PERMUTED layout: [bh][chunk:64][sub:4][d:32][slot:16] f16
//   slot order holds keys sigma = [0,1,2,3,8,9,10,11,4,5,6,7,12,13,14,15]
//   (involution) so the attn PV B-operand is exactly the lane's own packed
//   exp2(S) registers.  d rows 0..15 = V^T; rows 16..31 = pad, rows 16/20 = 1.0
//   (PV MFMA accumulates L = sum(exp) into acc reg 8 free), rest 0.
__global__ __launch_bounds__(256) void qkv_kernel(const float* __restrict__ x,
        const float* __restrict__ w, const float* __restrict__ bias,
        __fp16* __restrict__ Q, __fp16* __restrict__ K, __fp16* __restrict__ VT) {
    __shared__ __fp16 smv[64][16];   // [h*16+d][t-col] staging for V transpose
    const int t = threadIdx.x;
    const int wave = t >> 6, lane = t & 63;
    const int lq = lane & 15, g = lane >> 4;
    const int r0 = blockIdx.x*16;
    const int b = r0 >> 12, tt0 = r0 & (TT-1);

    // B-frag (x^T): lane holds x[r0+lq][s*16 + g*4 + j]
    h4 xb[4];
    const float* xrow = x + (size_t)(r0 + lq)*CC;
    #pragma unroll
    for (int s = 0; s < 4; s++) {
        float4 xv = *(const float4*)(xrow + s*16 + g*4);
        h2 lo = __builtin_amdgcn_cvt_pkrtz(xv.x, xv.y);
        h2 hi = __builtin_amdgcn_cvt_pkrtz(xv.z, xv.w);
        xb[s] = (h4){lo.x, lo.y, hi.x, hi.y};
    }

    #pragma unroll
    for (int j = 0; j < 3; j++) {
        const int nt = wave*3 + j;       // tile: o-range [nt*16, nt*16+16)
        const int o0 = nt*16;
        const float sc = (nt < 4) ? SCALE : 1.0f;
        float4 bv = *(const float4*)(bias + o0 + g*4);
        f4 acc = {bv.x*sc, bv.y*sc, bv.z*sc, bv.w*sc};
        #pragma unroll
        for (int s = 0; s < 4; s++) {
            float4 wv = *(const float4*)(w + (size_t)(o0 + lq)*CC + s*16 + g*4);
            h2 lo = __builtin_amdgcn_cvt_pkrtz(wv.x*sc, wv.y*sc);
            h2 hi = __builtin_amdgcn_cvt_pkrtz(wv.z*sc, wv.w*sc);
            h4 af = (h4){lo.x, lo.y, hi.x, hi.y};
            acc = __builtin_amdgcn_mfma_f32_16x16x16f16(af, xb[s], acc, 0, 0, 0);
        }
        h2 plo = __builtin_amdgcn_cvt_pkrtz(acc.x, acc.y);
        h2 phi = __builtin_amdgcn_cvt_pkrtz(acc.z, acc.w);
        h4 pk = (h4){plo.x, plo.y, phi.x, phi.y};
        if (nt < 8) {
            const int part = nt >> 2, h = nt & 3;
            __fp16* dst = (part == 0) ? Q : K;
            *(h4*)(dst + ((size_t)(b*HH + h)*TT + tt0 + lq)*DH + g*4) = pk;
        } else {
            const int h = nt - 8;
            smv[h*16 + g*4 + 0][lq] = pk.x;
            smv[h*16 + g*4 + 1][lq] = pk.y;
            smv[h*16 + g*4 + 2][lq] = pk.z;
            smv[h*16 + g*4 + 3][lq] = pk.w;
        }
    }
    __syncthreads();
    if (t < 64) {                        // row (h,d): 16 t-cols = one k16 group
        const int h = t >> 4, d = t & 15;
        uint4 v0 = *(const uint4*)&smv[t][0];   // keys 0..7
        uint4 v1 = *(const uint4*)&smv[t][8];   // keys 8..15
        // permuted slot order [0,1,2,3,8,9,10,11 | 4,5,6,7,12,13,14,15]
        uint4 pa = {v0.x, v0.y, v1.x, v1.y};    // slots 0..7
        uint4 pb = {v0.z, v0.w, v1.z, v1.w};    // slots 8..15
        __fp16* dst = VT + (size_t)(b*HH + h)*TT*32
                        + (size_t)(tt0 >> 6)*2048           // chunk
                        + (size_t)((tt0 & 63) >> 4)*512     // sub
                        + (size_t)d*16;                     // d row
        *(uint4*)dst = pa;
        *(uint4*)(dst + 8) = pb;
        const unsigned cb = (d == 0 || d == 4) ? 0x3C003C00u : 0u;
        const uint4 cv = {cb, cb, cb, cb};
        __fp16* dst2 = dst + 16*16;
        *(uint4*)dst2 = cv;
        *(uint4*)(dst2 + 8) = cv;
    }
}

// ---------------- Kernel B: flash attention, 64 q-rows/block, DEPTH-2 prefetch ----------------
// 512 blocks x 256 thr.  Round-6 structure (session best) with ONE change:
// 4-buffer register ring, loads issued TWO chunks (~900 cyc) ahead of use.
// Rationale: each wave reads each of its 16 chunks exactly once (no intra-wave
// reuse), so first-pass lines are cold (HBM ~900cyc, incl. cross-XCD writeback
// from qkv); the old depth-1 pipeline (~450cyc of compute ahead) covered L2
// latency but only half a cold miss.  Depth-2 covers the cold case too.
//  - XCD-head affinity: head = blockIdx & 7 -> per-XCD working set ~0.5MB.
//  - Swap-free P assembly via the key-permuted VT layout.
//  - Pad-ones rows 16/20 -> PV MFMA accumulates L = sum(exp) in acc reg 8 free.
__global__ __launch_bounds__(256) void attn_kernel(const __fp16* __restrict__ Q,
        const __fp16* __restrict__ K, const __fp16* __restrict__ VT,
        __fp16* __restrict__ yh) {
    __shared__ float Osm[4][2][64][9];   // [ksplit][qtile][lane][reg0..7, L]
    const int t = threadIdx.x;
    const int wave = t >> 6, lane = t & 63;
    const int l31 = lane & 31, hi = lane >> 5;
    const int head = blockIdx.x & 7;     // XCD-head affinity
    const int qt   = blockIdx.x >> 3;
    const int q0 = qt*64;
    const __fp16* Qh = Q  + (size_t)head*TT*DH;
    const __fp16* Kh = K  + (size_t)head*TT*DH;
    const __fp16* Vh = VT + (size_t)head*TT*32;

    // Q fragments (B-operand): col q = l31, d = hi*8 + j  -> 16B loads
    U4H8 qf0, qf1;
    qf0.u = *(const uint4*)(Qh + (size_t)(q0 + l31)*DH + hi*8);
    qf1.u = *(const uint4*)(Qh + (size_t)(q0 + 32 + l31)*DH + hi*8);

    const f16v Zf = {0.f,0.f,0.f,0.f,0.f,0.f,0.f,0.f,0.f,0.f,0.f,0.f,0.f,0.f,0.f,0.f};
    f16v O0 = Zf, O1 = Zf;

    const __fp16* kbase = Kh + (size_t)(wave*1024 + l31)*DH + hi*8;      // + c*1024 + kt*512
    const __fp16* vbase = Vh + (size_t)(wave*16)*2048 + l31*16 + hi*8;   // + c*2048 + s*512

    const int start = (blockIdx.x*5 + wave*3) & 15;   // per-(block,wave) phase

    uint4 kA[2], vA[4], kB[2], vB[4], kC[2], vC[4], kD[2], vD[4];

#define LOADC(c, KF, VF)                                                   \
    {  const size_t cc_ = (size_t)(c);                                     \
       _Pragma("unroll") for (int kt_ = 0; kt_ < 2; kt_++)                 \
           KF[kt_] = *(const uint4*)(kbase + cc_*1024 + kt_*512);          \
       _Pragma("unroll") for (int s_ = 0; s_ < 4; s_++)                    \
           VF[s_] = *(const uint4*)(vbase + cc_*2048 + s_*512);            \
    }

    LOADC(start, kA, vA)
    LOADC((start + 1) & 15, kB, vB)

// W_[m] = packed f16 pair of exp2 of S regs (2m, 2m+1).  With the key-permuted
// VT layout, B-frag of 16-key group g is exactly W_[4g..4g+3] on every lane.
#define PROC_TILE(S, O, VF)                                                        \
    {   float p_[16]; unsigned W_[8];                                              \
        _Pragma("unroll") for (int r_ = 0; r_ < 16; r_++)                          \
            p_[r_] = __builtin_amdgcn_exp2f(S[r_]);                                \
        _Pragma("unroll") for (int m_ = 0; m_ < 8; m_++)                           \
            W_[m_] = __builtin_bit_cast(unsigned,                                  \
                __builtin_amdgcn_cvt_pkrtz(p_[2*m_], p_[2*m_+1]));                 \
        _Pragma("unroll") for (int s2 = 0; s2 < 2; s2++) {                         \
            UWH8 bw_;                                                              \
            bw_.u[0] = W_[4*s2+0];  bw_.u[1] = W_[4*s2+1];                         \
            bw_.u[2] = W_[4*s2+2];  bw_.u[3] = W_[4*s2+3];                         \
            U4H8 vv_; vv_.u = VF[kt*2+s2];                                         \
            O = __builtin_amdgcn_mfma_f32_32x32x16_f16(vv_.h, bw_.h, O, 0,0,0);    \
        }                                                                          \
    }

#define ATTN_CHUNK(KF, VF)                                                         \
    _Pragma("unroll")                                                              \
    for (int kt = 0; kt < 2; kt++) {                                               \
        U4H8 ak_; ak_.u = KF[kt];                                                  \
        f16v S0 = __builtin_amdgcn_mfma_f32_32x32x16_f16(ak_.h, qf0.h, Zf, 0,0,0); \
        f16v S1 = __builtin_amdgcn_mfma_f32_32x32x16_f16(ak_.h, qf1.h, Zf, 0,0,0); \
        PROC_TILE(S0, O0, VF)                                                      \
        PROC_TILE(S1, O1, VF)                                                      \
    }

    // 4-stage rotation, unroll 4: every load issued 2 chunks ahead of its use.
    // Tail loads (it+4/it+5 on the last group) wrap via &15 -- redundant, harmless.
    for (int it = 0; it < 16; it += 4) {
        LOADC((start + it + 2) & 15, kC, vC)
        ATTN_CHUNK(kA, vA)
        LOADC((start + it + 3) & 15, kD, vD)
        ATTN_CHUNK(kB, vB)
        LOADC((start + it + 4) & 15, kA, vA)
        ATTN_CHUNK(kC, vC)
        LOADC((start + it + 5) & 15, kB, vB)
        ATTN_CHUNK(kD, vD)
    }
#undef ATTN_CHUNK
#undef PROC_TILE
#undef LOADC

    // split-K combine: O regs 0..7 are d = {0..3,8..11}+4*hi, reg 8 = L
    #pragma unroll
    for (int r = 0; r < 9; r++) {
        Osm[wave][0][lane][r] = O0[r];
        Osm[wave][1][lane][r] = O1[r];
    }
    __syncthreads();
    if (wave < 2) {
        const int qt2 = wave;
        float a[9];
        #pragma unroll
        for (int r = 0; r < 9; r++)
            a[r] = Osm[0][qt2][lane][r] + Osm[1][qt2][lane][r]
                 + Osm[2][qt2][lane][r] + Osm[3][qt2][lane][r];
        const float rinv = 1.f / a[8];
        h2 plo = __builtin_amdgcn_cvt_pkrtz(a[0]*rinv, a[1]*rinv);
        h2 phi = __builtin_amdgcn_cvt_pkrtz(a[2]*rinv, a[3]*rinv);
        h4 pk1 = (h4){plo.x, plo.y, phi.x, phi.y};
        plo = __builtin_amdgcn_cvt_pkrtz(a[4]*rinv, a[5]*rinv);
        phi = __builtin_amdgcn_cvt_pkrtz(a[6]*rinv, a[7]*rinv);
        h4 pk2 = (h4){plo.x, plo.y, phi.x, phi.y};
        const int b = head >> 2, hh = head & 3;
        const size_t q = (size_t)q0 + qt2*32 + l31;
        __fp16* dst = yh + ((size_t)b*TT + q)*CC + hh*DH + hi*4;   // d = hi*4
        *(h4*)dst = pk1;
        *(h4*)(dst + 8) = pk2;                                     // d = 8 + hi*4
    }
}

// ---------------- Kernel C: out = y @ w_proj^T + b_proj (round-0/6 proven version) ----------------
// 512 blocks x 256 thr: block = 16 rows; wave w -> o-range [w*16, w*16+16)
__global__ __launch_bounds__(256) void proj_kernel(const __fp16* __restrict__ yh,
        const float* __restrict__ w, const float* __restrict__ bias,
        float* __restrict__ out) {
    const int t = threadIdx.x;
    const int wave = t >> 6, lane = t & 63;
    const int lq = lane & 15, g = lane >> 4;
    const int r0 = blockIdx.x*16;
    const int o0 = wave*16;

    // B-frag (y^T): lane holds y[r0+lq][s*16 + g*4 + j]
    h4 yb[4];
    const __fp16* yrow = yh + (size_t)(r0 + lq)*CC;
    #pragma unroll
    for (int s = 0; s < 4; s++) yb[s] = *(const h4*)(yrow + s*16 + g*4);

    float4 bv = *(const float4*)(bias + o0 + g*4);
    f4 acc = {bv.x, bv.y, bv.z, bv.w};
    #pragma unroll
    for (int s = 0; s < 4; s++) {
        // A-frag (w): lane holds w[o0+lq][s*16 + g*4 + j]
        float4 wv = *(const float4*)(w + (size_t)(o0 + lq)*CC + s*16 + g*4);
        h2 lo = __builtin_amdgcn_cvt_pkrtz(wv.x, wv.y);
        h2 hi = __builtin_amdgcn_cvt_pkrtz(wv.z, wv.w);
        h4 af = (h4){lo.x, lo.y, hi.x, hi.y};
        acc = __builtin_amdgcn_mfma_f32_16x16x16f16(af, yb[s], acc, 0, 0, 0);
    }
    // D: lane holds out[r0+lq][o0 + g*4 .. +3] -> coalesced float4
    *(float4*)(out + (size_t)(r0 + lq)*CC + o0 + g*4) = (float4){acc.x, acc.y, acc.z, acc.w};
}

extern "C" void kernel_launch(void* const* d_in, const int* in_sizes, int n_in,
                              void* d_out, int out_size, void* d_ws, size_t ws_size,
                              hipStream_t stream) {
    const float* x      = (const float*)d_in[0];
    const float* w_attn = (const float*)d_in[1];
    const float* b_attn = (const float*)d_in[2];
    const float* w_proj = (const float*)d_in[3];
    const float* b_proj = (const float*)d_in[4];
    float* out = (float*)d_out;

    const size_t headszQK = (size_t)BB*HH*TT*DH;   // Q,K: 512K halves each
    const size_t vtsz     = (size_t)BB*HH*TT*32;   // VT (d-expanded): 1M halves
    __fp16* Q   = (__fp16*)d_ws;
    __fp16* K   = Q + headszQK;
    __fp16* VT  = K + headszQK;
    __fp16* yh  = VT + vtsz;

    qkv_kernel<<<NROW/16, 256, 0, stream>>>(x, w_attn, b_attn, Q, K, VT);
    attn_kernel<<<BB*HH*(TT/64), 256, 0, stream>>>(Q, K, VT, yh);
    proj_kernel<<<NROW/16, 256, 0, stream>>>(yh, w_proj, b_proj, out);
}

// Round 13
// 89.080 us; speedup vs baseline: 3.7814x; 1.0223x over previous
//
#include <hip/hip_runtime.h>
#include <math.h>

#define BB 2
#define TT 4096
#define CC 64
#define HH 4
#define DH 16
#define NROW (BB*TT)                 // 8192
#define SCALE 0.36067376022224085f   // 0.25 * log2(e)

typedef __fp16 h4 __attribute__((ext_vector_type(4)));
typedef __fp16 h2 __attribute__((ext_vector_type(2)));
typedef __fp16 h8 __attribute__((ext_vector_type(8)));
typedef float  f4 __attribute__((ext_vector_type(4)));
typedef float  f16v __attribute__((ext_vector_type(16)));

union U4H8 { uint4 u; h8 h; };
union UWH8 { unsigned u[4]; h8 h; };

// ================= SESSION-BEST CONFIGURATION (round 6, 88.7 us) =================
// Locked in after 12 rounds.  Verified-null levers: attn TLP (x3), MFMA shape,
// V density, asm scheduling, prefetch depth-2, qkv/proj restructure, fusion via
// coop-launch / grid-barrier / atomics (all worse).  Verified wins kept here:
// native 32x32x16 MFMA, k16-grouped key-permuted VT (dense V loads + swap-free
// P assembly), pad-ones softmax denominator, XCD-head affinity (L2-resident K/V).

// ---------------- Kernel A: qkv GEMM ----------------
// 512 blocks x 256 thr: block = 16 rows; wave w -> output tiles w*3..w*3+2 (of 12)
// Q,K: [bh][T][16] f16.
// VT k16-grouped, K-PERMUTED layout: [bh][chunk:64][sub:4][d:32][slot:16] f16
//   slot order holds keys sigma = [0,1,2,3,8,9,10,11,4,5,6,7,12,13,14,15]
//   (involution) so the attn PV B-operand is exactly the lane's own packed
//   exp2(S) registers.  d rows 0..15 = V^T; rows 16..31 = pad, rows 16/20 = 1.0
//   (PV MFMA accumulates L = sum(exp) into acc reg 8 free), rest 0.
__global__ __launch_bounds__(256) void qkv_kernel(const float* __restrict__ x,
        const float* __restrict__ w, const float* __restrict__ bias,
        __fp16* __restrict__ Q, __fp16* __restrict__ K, __fp16* __restrict__ VT) {
    __shared__ __fp16 smv[64][16];   // [h*16+d][t-col] staging for V transpose
    const int t = threadIdx.x;
    const int wave = t >> 6, lane = t & 63;
    const int lq = lane & 15, g = lane >> 4;
    const int r0 = blockIdx.x*16;
    const int b = r0 >> 12, tt0 = r0 & (TT-1);

    // B-frag (x^T): lane holds x[r0+lq][s*16 + g*4 + j]
    h4 xb[4];
    const float* xrow = x + (size_t)(r0 + lq)*CC;
    #pragma unroll
    for (int s = 0; s < 4; s++) {
        float4 xv = *(const float4*)(xrow + s*16 + g*4);
        h2 lo = __builtin_amdgcn_cvt_pkrtz(xv.x, xv.y);
        h2 hi = __builtin_amdgcn_cvt_pkrtz(xv.z, xv.w);
        xb[s] = (h4){lo.x, lo.y, hi.x, hi.y};
    }

    #pragma unroll
    for (int j = 0; j < 3; j++) {
        const int nt = wave*3 + j;       // tile: o-range [nt*16, nt*16+16)
        const int o0 = nt*16;
        const float sc = (nt < 4) ? SCALE : 1.0f;
        float4 bv = *(const float4*)(bias + o0 + g*4);
        f4 acc = {bv.x*sc, bv.y*sc, bv.z*sc, bv.w*sc};
        #pragma unroll
        for (int s = 0; s < 4; s++) {
            float4 wv = *(const float4*)(w + (size_t)(o0 + lq)*CC + s*16 + g*4);
            h2 lo = __builtin_amdgcn_cvt_pkrtz(wv.x*sc, wv.y*sc);
            h2 hi = __builtin_amdgcn_cvt_pkrtz(wv.z*sc, wv.w*sc);
            h4 af = (h4){lo.x, lo.y, hi.x, hi.y};
            acc = __builtin_amdgcn_mfma_f32_16x16x16f16(af, xb[s], acc, 0, 0, 0);
        }
        h2 plo = __builtin_amdgcn_cvt_pkrtz(acc.x, acc.y);
        h2 phi = __builtin_amdgcn_cvt_pkrtz(acc.z, acc.w);
        h4 pk = (h4){plo.x, plo.y, phi.x, phi.y};
        if (nt < 8) {
            const int part = nt >> 2, h = nt & 3;
            __fp16* dst = (part == 0) ? Q : K;
            *(h4*)(dst + ((size_t)(b*HH + h)*TT + tt0 + lq)*DH + g*4) = pk;
        } else {
            const int h = nt - 8;
            smv[h*16 + g*4 + 0][lq] = pk.x;
            smv[h*16 + g*4 + 1][lq] = pk.y;
            smv[h*16 + g*4 + 2][lq] = pk.z;
            smv[h*16 + g*4 + 3][lq] = pk.w;
        }
    }
    __syncthreads();
    if (t < 64) {                        // row (h,d): 16 t-cols = one k16 group
        const int h = t >> 4, d = t & 15;
        uint4 v0 = *(const uint4*)&smv[t][0];   // keys 0..7
        uint4 v1 = *(const uint4*)&smv[t][8];   // keys 8..15
        // permuted slot order [0,1,2,3,8,9,10,11 | 4,5,6,7,12,13,14,15]
        uint4 pa = {v0.x, v0.y, v1.x, v1.y};    // slots 0..7
        uint4 pb = {v0.z, v0.w, v1.z, v1.w};    // slots 8..15
        __fp16* dst = VT + (size_t)(b*HH + h)*TT*32
                        + (size_t)(tt0 >> 6)*2048           // chunk
                        + (size_t)((tt0 & 63) >> 4)*512     // sub
                        + (size_t)d*16;                     // d row
        *(uint4*)dst = pa;
        *(uint4*)(dst + 8) = pb;
        const unsigned cb = (d == 0 || d == 4) ? 0x3C003C00u : 0u;
        const uint4 cv = {cb, cb, cb, cb};
        __fp16* dst2 = dst + 16*16;
        *(uint4*)dst2 = cv;
        *(uint4*)(dst2 + 8) = cv;
    }
}

// ---------------- Kernel B: flash attention, 64 q-rows/block, native 32x32x16 MFMA ----------------
// 512 blocks x 256 thr.
//  - XCD-head affinity: head = blockIdx & 7 -> per-XCD K/VT working set ~0.5MB,
//    L2-resident (was 3x HBM re-fetch).
//  - Swap-free P assembly via the key-permuted VT layout.
//  - Pad-ones rows 16/20 -> PV MFMA accumulates L = sum(exp) in acc reg 8 free.
//  - Depth-1 ring prefetch, per-(block,wave) phase stagger.
__global__ __launch_bounds__(256) void attn_kernel(const __fp16* __restrict__ Q,
        const __fp16* __restrict__ K, const __fp16* __restrict__ VT,
        __fp16* __restrict__ yh) {
    __shared__ float Osm[4][2][64][9];   // [ksplit][qtile][lane][reg0..7, L]
    const int t = threadIdx.x;
    const int wave = t >> 6, lane = t & 63;
    const int l31 = lane & 31, hi = lane >> 5;
    const int head = blockIdx.x & 7;     // XCD-head affinity
    const int qt   = blockIdx.x >> 3;
    const int q0 = qt*64;
    const __fp16* Qh = Q  + (size_t)head*TT*DH;
    const __fp16* Kh = K  + (size_t)head*TT*DH;
    const __fp16* Vh = VT + (size_t)head*TT*32;

    // Q fragments (B-operand): col q = l31, d = hi*8 + j  -> 16B loads
    U4H8 qf0, qf1;
    qf0.u = *(const uint4*)(Qh + (size_t)(q0 + l31)*DH + hi*8);
    qf1.u = *(const uint4*)(Qh + (size_t)(q0 + 32 + l31)*DH + hi*8);

    const f16v Zf = {0.f,0.f,0.f,0.f,0.f,0.f,0.f,0.f,0.f,0.f,0.f,0.f,0.f,0.f,0.f,0.f};
    f16v O0 = Zf, O1 = Zf;

    const __fp16* kbase = Kh + (size_t)(wave*1024 + l31)*DH + hi*8;      // + c*1024 + kt*512
    const __fp16* vbase = Vh + (size_t)(wave*16)*2048 + l31*16 + hi*8;   // + c*2048 + s*512

    const int start = (blockIdx.x*5 + wave*3) & 15;   // per-(block,wave) phase

    uint4 ka[2], va[4], kb[2], vb[4];

#define LOADC(c, KF, VF)                                                   \
    {  const size_t cc_ = (size_t)(c);                                     \
       _Pragma("unroll") for (int kt_ = 0; kt_ < 2; kt_++)                 \
           KF[kt_] = *(const uint4*)(kbase + cc_*1024 + kt_*512);          \
       _Pragma("unroll") for (int s_ = 0; s_ < 4; s_++)                    \
           VF[s_] = *(const uint4*)(vbase + cc_*2048 + s_*512);            \
    }

    LOADC(start, ka, va)

// W_[m] = packed f16 pair of exp2 of S regs (2m, 2m+1).  With the key-permuted
// VT layout, B-frag of 16-key group g is exactly W_[4g..4g+3] on every lane:
// hi=0 lanes hold keys {0-3,8-11} = permuted slots 0..7; hi=1 lanes hold keys
// {4-7,12-15} = permuted slots 8..15.  No cross-lane movement needed.
#define PROC_TILE(S, O, VF)                                                        \
    {   float p_[16]; unsigned W_[8];                                              \
        _Pragma("unroll") for (int r_ = 0; r_ < 16; r_++)                          \
            p_[r_] = __builtin_amdgcn_exp2f(S[r_]);                                \
        _Pragma("unroll") for (int m_ = 0; m_ < 8; m_++)                           \
            W_[m_] = __builtin_bit_cast(unsigned,                                  \
                __builtin_amdgcn_cvt_pkrtz(p_[2*m_], p_[2*m_+1]));                 \
        _Pragma("unroll") for (int s2 = 0; s2 < 2; s2++) {                         \
            UWH8 bw_;                                                              \
            bw_.u[0] = W_[4*s2+0];  bw_.u[1] = W_[4*s2+1];                         \
            bw_.u[2] = W_[4*s2+2];  bw_.u[3] = W_[4*s2+3];                         \
            U4H8 vv_; vv_.u = VF[kt*2+s2];                                         \
            O = __builtin_amdgcn_mfma_f32_32x32x16_f16(vv_.h, bw_.h, O, 0,0,0);    \
        }                                                                          \
    }

#define ATTN_CHUNK(KF, VF)                                                         \
    _Pragma("unroll")                                                              \
    for (int kt = 0; kt < 2; kt++) {                                               \
        U4H8 ak_; ak_.u = KF[kt];                                                  \
        f16v S0 = __builtin_amdgcn_mfma_f32_32x32x16_f16(ak_.h, qf0.h, Zf, 0,0,0); \
        f16v S1 = __builtin_amdgcn_mfma_f32_32x32x16_f16(ak_.h, qf1.h, Zf, 0,0,0); \
        PROC_TILE(S0, O0, VF)                                                      \
        PROC_TILE(S1, O1, VF)                                                      \
    }

    for (int it = 0; it < 16; it += 2) {
        LOADC((start + it + 1) & 15, kb, vb)
        ATTN_CHUNK(ka, va)
        LOADC((start + it + 2) & 15, ka, va)   // wraps on last iter (redundant, harmless)
        ATTN_CHUNK(kb, vb)
    }
#undef ATTN_CHUNK
#undef PROC_TILE
#undef LOADC

    // split-K combine: O regs 0..7 are d = {0..3,8..11}+4*hi, reg 8 = L
    #pragma unroll
    for (int r = 0; r < 9; r++) {
        Osm[wave][0][lane][r] = O0[r];
        Osm[wave][1][lane][r] = O1[r];
    }
    __syncthreads();
    if (wave < 2) {
        const int qt2 = wave;
        float a[9];
        #pragma unroll
        for (int r = 0; r < 9; r++)
            a[r] = Osm[0][qt2][lane][r] + Osm[1][qt2][lane][r]
                 + Osm[2][qt2][lane][r] + Osm[3][qt2][lane][r];
        const float rinv = 1.f / a[8];
        h2 plo = __builtin_amdgcn_cvt_pkrtz(a[0]*rinv, a[1]*rinv);
        h2 phi = __builtin_amdgcn_cvt_pkrtz(a[2]*rinv, a[3]*rinv);
        h4 pk1 = (h4){plo.x, plo.y, phi.x, phi.y};
        plo = __builtin_amdgcn_cvt_pkrtz(a[4]*rinv, a[5]*rinv);
        phi = __builtin_amdgcn_cvt_pkrtz(a[6]*rinv, a[7]*rinv);
        h4 pk2 = (h4){plo.x, plo.y, phi.x, phi.y};
        const int b = head >> 2, hh = head & 3;
        const size_t q = (size_t)q0 + qt2*32 + l31;
        __fp16* dst = yh + ((size_t)b*TT + q)*CC + hh*DH + hi*4;   // d = hi*4
        *(h4*)dst = pk1;
        *(h4*)(dst + 8) = pk2;                                     // d = 8 + hi*4
    }
}

// ---------------- Kernel C: out = y @ w_proj^T + b_proj ----------------
// 512 blocks x 256 thr: block = 16 rows; wave w -> o-range [w*16, w*16+16)
__global__ __launch_bounds__(256) void proj_kernel(const __fp16* __restrict__ yh,
        const float* __restrict__ w, const float* __restrict__ bias,
        float* __restrict__ out) {
    const int t = threadIdx.x;
    const int wave = t >> 6, lane = t & 63;
    const int lq = lane & 15, g = lane >> 4;
    const int r0 = blockIdx.x*16;
    const int o0 = wave*16;

    // B-frag (y^T): lane holds y[r0+lq][s*16 + g*4 + j]
    h4 yb[4];
    const __fp16* yrow = yh + (size_t)(r0 + lq)*CC;
    #pragma unroll
    for (int s = 0; s < 4; s++) yb[s] = *(const h4*)(yrow + s*16 + g*4);

    float4 bv = *(const float4*)(bias + o0 + g*4);
    f4 acc = {bv.x, bv.y, bv.z, bv.w};
    #pragma unroll
    for (int s = 0; s < 4; s++) {
        // A-frag (w): lane holds w[o0+lq][s*16 + g*4 + j]
        float4 wv = *(const float4*)(w + (size_t)(o0 + lq)*CC + s*16 + g*4);
        h2 lo = __builtin_amdgcn_cvt_pkrtz(wv.x, wv.y);
        h2 hi = __builtin_amdgcn_cvt_pkrtz(wv.z, wv.w);
        h4 af = (h4){lo.x, lo.y, hi.x, hi.y};
        acc = __builtin_amdgcn_mfma_f32_16x16x16f16(af, yb[s], acc, 0, 0, 0);
    }
    // D: lane holds out[r0+lq][o0 + g*4 .. +3] -> coalesced float4
    *(float4*)(out + (size_t)(r0 + lq)*CC + o0 + g*4) = (float4){acc.x, acc.y, acc.z, acc.w};
}

extern "C" void kernel_launch(void* const* d_in, const int* in_sizes, int n_in,
                              void* d_out, int out_size, void* d_ws, size_t ws_size,
                              hipStream_t stream) {
    const float* x      = (const float*)d_in[0];
    const float* w_attn = (const float*)d_in[1];
    const float* b_attn = (const float*)d_in[2];
    const float* w_proj = (const float*)d_in[3];
    const float* b_proj = (const float*)d_in[4];
    float* out = (float*)d_out;

    const size_t headszQK = (size_t)BB*HH*TT*DH;   // Q,K: 512K halves each
    const size_t vtsz     = (size_t)BB*HH*TT*32;   // VT (d-expanded): 1M halves
    __fp16* Q   = (__fp16*)d_ws;
    __fp16* K   = Q + headszQK;
    __fp16* VT  = K + headszQK;
    __fp16* yh  = VT + vtsz;

    qkv_kernel<<<NROW/16, 256, 0, stream>>>(x, w_attn, b_attn, Q, K, VT);
    attn_kernel<<<BB*HH*(TT/64), 256, 0, stream>>>(Q, K, VT, yh);
    proj_kernel<<<NROW/16, 256, 0, stream>>>(yh, w_proj, b_proj, out);
}